// Round 1
// baseline (2163.955 us; speedup 1.0000x reference)
//
#include <hip/hip_runtime.h>
#include <cfloat>
#include <cmath>

#define K_CODES 8192
#define DIM 256
#define MQ 128
#define NKT 128
#define KSPLIT 4

// ---------------------------------------------------------------- norms
__global__ __launch_bounds__(256) void norms_kernel(const float* __restrict__ E,
                                                    float* __restrict__ norms) {
    int k = blockIdx.x * 256 + threadIdx.x;
    float s = 0.f;
#pragma unroll 8
    for (int d = 0; d < DIM; ++d) { float v = E[(size_t)d * K_CODES + k]; s += v * v; }
    norms[k] = s;
}

// ------------------------------------------------- argmax GEMM (fp32)
// score_k = 2*x.Ek - ||Ek||^2 ; running argmax, first-max tie-break.
// grid (KSPLIT, N/MQ), block 256 (16x16 threads, 8x8 micro-tile)
__global__ __launch_bounds__(256) void argmax_kernel(
        const float* __restrict__ X, const float* __restrict__ E,
        const float* __restrict__ norms, float* __restrict__ pbest,
        int* __restrict__ pidx, int N) {
    __shared__ float Xs[16][132];   // +4 pad: breaks transpose-write conflicts, keeps 16B align
    __shared__ float Es[16][NKT];
    __shared__ float rv[MQ][16];
    __shared__ int   ri[MQ][16];

    const int t  = threadIdx.x;
    const int tx = t & 15, ty = t >> 4;
    const int part  = blockIdx.x;
    const int q0    = blockIdx.y * MQ;
    const int kpart = K_CODES / KSPLIT;

    float best[8];
    int   bidx[8];
#pragma unroll
    for (int i = 0; i < 8; ++i) { best[i] = -FLT_MAX; bidx[i] = 0; }

    for (int kt = 0; kt < kpart / NKT; ++kt) {
        const int k0 = part * kpart + kt * NKT;
        float acc[8][8];
#pragma unroll
        for (int i = 0; i < 8; ++i)
#pragma unroll
            for (int j = 0; j < 8; ++j) acc[i][j] = 0.f;

        for (int d0 = 0; d0 < DIM; d0 += 16) {
            // stage E tile [16 d][128 k] (row-major in k: coalesced float4)
#pragma unroll
            for (int i = 0; i < 2; ++i) {
                int f = t + i * 256;
                int row = f >> 5, c4 = f & 31;
                *(float4*)&Es[row][c4 * 4] =
                    *(const float4*)&E[(size_t)(d0 + row) * K_CODES + k0 + c4 * 4];
            }
            // stage X tile transposed -> Xs[d][q]
#pragma unroll
            for (int i = 0; i < 2; ++i) {
                int f = t + i * 256;
                int q = f >> 2, c4 = f & 3;
                float4 v = *(const float4*)&X[(size_t)(q0 + q) * DIM + d0 + c4 * 4];
                Xs[c4 * 4 + 0][q] = v.x;
                Xs[c4 * 4 + 1][q] = v.y;
                Xs[c4 * 4 + 2][q] = v.z;
                Xs[c4 * 4 + 3][q] = v.w;
            }
            __syncthreads();
#pragma unroll
            for (int d = 0; d < 16; ++d) {
                float4 a0 = *(const float4*)&Xs[d][ty * 8];
                float4 a1 = *(const float4*)&Xs[d][ty * 8 + 4];
                float4 b0 = *(const float4*)&Es[d][tx * 8];
                float4 b1 = *(const float4*)&Es[d][tx * 8 + 4];
                float a[8] = {a0.x, a0.y, a0.z, a0.w, a1.x, a1.y, a1.z, a1.w};
                float b[8] = {b0.x, b0.y, b0.z, b0.w, b1.x, b1.y, b1.z, b1.w};
#pragma unroll
                for (int i = 0; i < 8; ++i)
#pragma unroll
                    for (int j = 0; j < 8; ++j)
                        acc[i][j] += a[i] * b[j];
            }
            __syncthreads();
        }
        // fold norms + update running argmax (k ascending within thread -> first-max)
        float nrm[8];
#pragma unroll
        for (int j = 0; j < 8; ++j) nrm[j] = norms[k0 + tx * 8 + j];
#pragma unroll
        for (int i = 0; i < 8; ++i)
#pragma unroll
            for (int j = 0; j < 8; ++j) {
                float s = 2.f * acc[i][j] - nrm[j];
                if (s > best[i]) { best[i] = s; bidx[i] = k0 + tx * 8 + j; }
            }
    }

    // cross-thread (tx) reduction per query row
#pragma unroll
    for (int i = 0; i < 8; ++i) {
        rv[ty * 8 + i][tx] = best[i];
        ri[ty * 8 + i][tx] = bidx[i];
    }
    __syncthreads();
    if (t < MQ) {
        float b = -FLT_MAX; int bi = 0;
#pragma unroll
        for (int j = 0; j < 16; ++j) {
            float v = rv[t][j]; int id = ri[t][j];
            if (v > b || (v == b && id < bi)) { b = v; bi = id; }
        }
        pbest[(size_t)part * N + q0 + t] = b;
        pidx [(size_t)part * N + q0 + t] = bi;
    }
}

// ------------------------------------------------- combine K-split partials
__global__ __launch_bounds__(256) void combine_kernel(
        const float* __restrict__ pbest, const int* __restrict__ pidx,
        int* __restrict__ idx, int* __restrict__ counts,
        float* __restrict__ out_idx_f, int N) {
    int q = blockIdx.x * 256 + threadIdx.x;
    float b = -FLT_MAX; int bi = 0;
#pragma unroll
    for (int p = 0; p < KSPLIT; ++p) {            // parts ascending in k: strict > keeps min-k on tie
        float v = pbest[(size_t)p * N + q]; int id = pidx[(size_t)p * N + q];
        if (v > b) { b = v; bi = id; }
    }
    idx[q] = bi;
    out_idx_f[q] = (float)bi;
    atomicAdd(&counts[bi], 1);
}

// ------------------------------------------------- gather quantized + MSE partial
__global__ __launch_bounds__(256) void gather_loss(
        const float* __restrict__ X, const float* __restrict__ E,
        const int* __restrict__ idx, float* __restrict__ outq,
        float* __restrict__ loss_sum) {
    int q = blockIdx.x, t = threadIdx.x;
    int k = idx[q];                       // wave-uniform -> scalar broadcast
    float e = E[(size_t)t * K_CODES + k]; // column gather (L3-resident E)
    float x = X[(size_t)q * DIM + t];
    outq[(size_t)q * DIM + t] = x + (e - x);   // straight-through value == e (mimic ref rounding)
    float d = e - x;
    float v = d * d;
#pragma unroll
    for (int off = 32; off; off >>= 1) v += __shfl_down(v, off, 64);
    __shared__ float red[4];
    if ((t & 63) == 0) red[t >> 6] = v;
    __syncthreads();
    if (t == 0) atomicAdd(loss_sum, red[0] + red[1] + red[2] + red[3]);
}

// ------------------------------------------------- scalars: vq_loss + usage loss
__global__ __launch_bounds__(256) void finalize_kernel(
        const int* __restrict__ counts, const float* __restrict__ loss_sum,
        float* __restrict__ out_scalars, int N) {
    int t = threadIdx.x;
    float ent = 0.f;
    for (int k = t; k < K_CODES; k += 256) {
        float p = (float)counts[k] / (float)N;
        ent -= p * logf(p + 1e-10f);
    }
#pragma unroll
    for (int off = 32; off; off >>= 1) ent += __shfl_down(ent, off, 64);
    __shared__ float red[4];
    if ((t & 63) == 0) red[t >> 6] = ent;
    __syncthreads();
    if (t == 0) {
        float e = red[0] + red[1] + red[2] + red[3];
        float mse = loss_sum[0] / (float)(N * DIM);
        out_scalars[0] = 1.1f * mse;                       // e_latent + 0.1*q_latent
        out_scalars[1] = -0.1f * (e / logf((float)K_CODES));
    }
}

extern "C" void kernel_launch(void* const* d_in, const int* in_sizes, int n_in,
                              void* d_out, int out_size, void* d_ws, size_t ws_size,
                              hipStream_t stream) {
    const float* X = (const float*)d_in[0];   // [32,32,32,256] fp32
    const float* E = (const float*)d_in[1];   // [256,8192] fp32
    const int N = in_sizes[0] / DIM;          // 32768

    float* out        = (float*)d_out;
    float* outq       = out;                          // N*DIM
    float* out_idx_f  = out + (size_t)N * DIM;        // N  (indices as f32)
    float* out_scal   = out_idx_f + N;                // 2 scalars

    float* wsf    = (float*)d_ws;
    int*   counts = (int*)wsf;                        // [8192] (zeroed)
    float* loss   = wsf + 8192;                       // [1]    (zeroed)
    float* norms  = wsf + 8448;                       // [8192]
    int*   idx    = (int*)(wsf + 16640);              // [N]
    float* pbest  = wsf + 16640 + N;                  // [KSPLIT*N]
    int*   pidx   = (int*)(pbest + (size_t)KSPLIT * N);

    hipMemsetAsync(d_ws, 0, (8192 + 64) * sizeof(float), stream);
    norms_kernel<<<K_CODES / 256, 256, 0, stream>>>(E, norms);
    argmax_kernel<<<dim3(KSPLIT, N / MQ), 256, 0, stream>>>(X, E, norms, pbest, pidx, N);
    combine_kernel<<<N / 256, 256, 0, stream>>>(pbest, pidx, idx, counts, out_idx_f, N);
    gather_loss<<<N, 256, 0, stream>>>(X, E, idx, outq, loss);
    finalize_kernel<<<1, 256, 0, stream>>>(counts, loss, out_scal, N);
}

// Round 2
// 853.322 us; speedup vs baseline: 2.5359x; 2.5359x over previous
//
#include <hip/hip_runtime.h>
#include <cfloat>
#include <cmath>

typedef short short8 __attribute__((ext_vector_type(8)));
typedef unsigned short ushort8 __attribute__((ext_vector_type(8)));
typedef float f32x16 __attribute__((ext_vector_type(16)));

#define K_CODES 8192
#define DIM 256
#define NQ_TOTAL 32768
#define TQ 128
#define TC 128
#define CSPLIT 8
#define CT_PER_BLOCK 8   /* 8192/128/CSPLIT */

/* ws layout (byte offsets) */
#define WS_COUNTS 0          /* int[8192]            32 KB (zeroed) */
#define WS_LOSSQ  32768      /* float[32768]        128 KB */
#define WS_NORMS  163840     /* float[8192]          32 KB */
#define WS_PVAL   196608     /* float[8*32768*3]      3 MB */
#define WS_PIDX   3342336    /* int  [8*32768*3]      3 MB */
#define WS_ET     6488064    /* float[8192*256]       8 MB */
#define WS_AHI    14876672   /* ushort[8192*256]      4 MB */
#define WS_ALO    19070976   /* ushort[8192*256]      4 MB */
#define WS_BHI    23265280   /* ushort[32768*256]    16 MB */
#define WS_BLO    40042496   /* ushort[32768*256]    16 MB */

__device__ inline unsigned short f32_to_bf16_rne(float x) {
    unsigned u = __builtin_bit_cast(unsigned, x);
    unsigned r = u + 0x7FFFu + ((u >> 16) & 1u);
    return (unsigned short)(r >> 16);
}
__device__ inline float bf16_to_f32(unsigned short h) {
    unsigned u = ((unsigned)h) << 16;
    return __builtin_bit_cast(float, u);
}
__device__ inline void split_bf16(float x, unsigned short& hi, unsigned short& lo) {
    hi = f32_to_bf16_rne(x);
    lo = f32_to_bf16_rne(x - bf16_to_f32(hi));
}
__device__ inline void ins3(float v, int c, float& v1, int& i1,
                            float& v2, int& i2, float& v3, int& i3) {
    bool g1 = v > v1, g2 = v > v2;
    v3 = g2 ? v2 : v;              i3 = g2 ? i2 : c;
    v2 = g2 ? (g1 ? v1 : v) : v2;  i2 = g2 ? (g1 ? i1 : c) : i2;
    v1 = g1 ? v : v1;              i1 = g1 ? c : i1;
}

// ---------------------------------------------------------------- norms (fp32, exact)
__global__ __launch_bounds__(256) void norms_kernel(const float* __restrict__ E,
                                                    float* __restrict__ norms) {
    int k = blockIdx.x * 256 + threadIdx.x;
    float s = 0.f;
#pragma unroll 8
    for (int d = 0; d < DIM; ++d) { float v = E[(size_t)d * K_CODES + k]; s += v * v; }
    norms[k] = s;
}

// ---------------------------------------------------------------- pack X -> frag-linear bf16 hi/lo
// chunk(q,d0): qt=q>>7, nt=(q>>5)&3, lq=q&31, s=d0>>4, h=(d0>>3)&1, lane=lq+32h
__global__ __launch_bounds__(256) void pack_X(const float* __restrict__ X,
        unsigned short* __restrict__ Bhi, unsigned short* __restrict__ Blo) {
    int id = blockIdx.x * 256 + threadIdx.x;      // 1048576 total
    int q = id >> 5, db = id & 31;
    const float* src = X + (size_t)q * DIM + db * 8;
    float4 a = *(const float4*)src, b = *(const float4*)(src + 4);
    float xs[8] = {a.x, a.y, a.z, a.w, b.x, b.y, b.z, b.w};
    ushort8 vh, vl;
#pragma unroll
    for (int i = 0; i < 8; ++i) { unsigned short h, l; split_bf16(xs[i], h, l); vh[i] = h; vl[i] = l; }
    int qt = q >> 7, nt = (q >> 5) & 3, lq = q & 31, s = db >> 1, hh = db & 1;
    int lane = lq + 32 * hh;
    size_t chunk = ((((size_t)qt * 16 + s) * 4 + nt) * 64 + lane) * 8;
    *(ushort8*)&Bhi[chunk] = vh;
    *(ushort8*)&Blo[chunk] = vl;
}

// ---------------------------------------------------------------- pack E -> A frags + fp32 E^T
__global__ __launch_bounds__(256) void pack_E(const float* __restrict__ E,
        unsigned short* __restrict__ Ahi, unsigned short* __restrict__ Alo,
        float* __restrict__ ET) {
    int id = blockIdx.x * 256 + threadIdx.x;      // 262144 total
    int db = id >> 13, c = id & 8191;
    float xs[8];
#pragma unroll
    for (int j = 0; j < 8; ++j) xs[j] = E[(size_t)(db * 8 + j) * K_CODES + c];
    // fp32 transpose for exact rescore + gather
    float4 f0 = {xs[0], xs[1], xs[2], xs[3]}, f1 = {xs[4], xs[5], xs[6], xs[7]};
    *(float4*)&ET[(size_t)c * DIM + db * 8]     = f0;
    *(float4*)&ET[(size_t)c * DIM + db * 8 + 4] = f1;
    ushort8 vh, vl;
#pragma unroll
    for (int j = 0; j < 8; ++j) { unsigned short h, l; split_bf16(xs[j], h, l); vh[j] = h; vl[j] = l; }
    int ct = c >> 7, mt = (c >> 5) & 3, lc = c & 31, s = db >> 1, hh = db & 1;
    int lane = lc + 32 * hh;
    size_t chunk = ((((size_t)ct * 16 + s) * 4 + mt) * 64 + lane) * 8;
    *(ushort8*)&Ahi[chunk] = vh;
    *(ushort8*)&Alo[chunk] = vl;
}

// ---------------------------------------------------------------- MFMA argmax (bf16x3 split precision)
// grid (CSPLIT, 256 query-tiles), 256 threads = 4 waves, wave = 64 codes x 64 queries
__global__ __launch_bounds__(256) void argmax_mfma(
        const unsigned short* __restrict__ Ahi, const unsigned short* __restrict__ Alo,
        const unsigned short* __restrict__ Bhi, const unsigned short* __restrict__ Blo,
        const float* __restrict__ norms,
        float* __restrict__ pval, int* __restrict__ pidx) {
    __shared__ __align__(16) unsigned short sst[16384];  // A 16KB | B 16KB, group-linear
    __shared__ float pvs[4][128][3];
    __shared__ int   pis[4][128][3];

    const int tid = threadIdx.x;
    const int lane = tid & 63, w = tid >> 6;
    const int wm = w & 1, wn = w >> 1;     // wave -> (code half, query half)
    const int h = lane >> 5;
    const int cs = blockIdx.x, qt = blockIdx.y;

    float v1[2], v2[2], v3[2]; int i1[2], i2[2], i3[2];
#pragma unroll
    for (int nt = 0; nt < 2; ++nt) { v1[nt] = v2[nt] = v3[nt] = -FLT_MAX; i1[nt] = i2[nt] = i3[nt] = 0; }

    for (int ctl = 0; ctl < CT_PER_BLOCK; ++ctl) {
        const int ctg = cs * CT_PER_BLOCK + ctl;
        f32x16 acc[2][2];
#pragma unroll
        for (int mt = 0; mt < 2; ++mt)
#pragma unroll
            for (int nt = 0; nt < 2; ++nt)
#pragma unroll
                for (int r = 0; r < 16; ++r) acc[mt][nt][r] = 0.f;

        for (int st = 0; st < 8; ++st) {          // D-loop: 8 stages x BK=32
            __syncthreads();                      // previous stage's readers done
#pragma unroll
            for (int i = 0; i < 8; ++i) {         // 8 x 1KB wave-loads, 32KB/stage total
                int g = w * 8 + i;
                int isB = g >> 4, gg = g & 15;
                int hilo = gg >> 3, s2 = (gg >> 2) & 1, t4 = gg & 3;
                int sg = st * 2 + s2;
                const unsigned short* base = isB ? (hilo ? Blo : Bhi) : (hilo ? Alo : Ahi);
                int tile = isB ? qt : ctg;
                const unsigned short* src = base + ((((size_t)tile * 16 + sg) * 4 + t4) * 64 + lane) * 8;
                unsigned short* dst = &sst[isB * 8192 + ((hilo * 2 + s2) * 4 + t4) * 512];
                __builtin_amdgcn_global_load_lds(
                    (const __attribute__((address_space(1))) unsigned int*)src,
                    (__attribute__((address_space(3))) unsigned int*)dst, 16, 0, 0);
            }
            __syncthreads();                      // drains vmcnt -> LDS visible
#pragma unroll
            for (int s = 0; s < 2; ++s) {
                short8 ah[2], al[2], bh[2], bl[2];
#pragma unroll
                for (int mt = 0; mt < 2; ++mt) {
                    ah[mt] = *(const short8*)&sst[((0 + s) * 4 + wm * 2 + mt) * 512 + lane * 8];
                    al[mt] = *(const short8*)&sst[((2 + s) * 4 + wm * 2 + mt) * 512 + lane * 8];
                }
#pragma unroll
                for (int nt = 0; nt < 2; ++nt) {
                    bh[nt] = *(const short8*)&sst[8192 + ((0 + s) * 4 + wn * 2 + nt) * 512 + lane * 8];
                    bl[nt] = *(const short8*)&sst[8192 + ((2 + s) * 4 + wn * 2 + nt) * 512 + lane * 8];
                }
#pragma unroll
                for (int mt = 0; mt < 2; ++mt)
#pragma unroll
                    for (int nt = 0; nt < 2; ++nt) {
                        acc[mt][nt] = __builtin_amdgcn_mfma_f32_32x32x16_bf16(ah[mt], bh[nt], acc[mt][nt], 0, 0, 0);
                        acc[mt][nt] = __builtin_amdgcn_mfma_f32_32x32x16_bf16(ah[mt], bl[nt], acc[mt][nt], 0, 0, 0);
                        acc[mt][nt] = __builtin_amdgcn_mfma_f32_32x32x16_bf16(al[mt], bh[nt], acc[mt][nt], 0, 0, 0);
                    }
            }
        }
        // epilogue: fold norms, guarded top-3 insert (codes ascending -> first-max kept)
        const int cbase = ctg * TC;
#pragma unroll
        for (int mt = 0; mt < 2; ++mt) {
            const int cb = cbase + (wm * 2 + mt) * 32 + 4 * h;
#pragma unroll
            for (int r = 0; r < 16; ++r) {
                const int row = (r & 3) + 8 * (r >> 2);
                const int code = cb + row;
                const float nrm = norms[code];
#pragma unroll
                for (int nt = 0; nt < 2; ++nt) {
                    float v = 2.f * acc[mt][nt][r] - nrm;
                    if (v > v3[nt]) ins3(v, code, v1[nt], i1[nt], v2[nt], i2[nt], v3[nt], i3[nt]);
                }
            }
        }
    }
    // merge 4 partial top-3s per query (wm x h) -> ws partials
    const int slot = wm * 2 + h;
#pragma unroll
    for (int nt = 0; nt < 2; ++nt) {
        int ql = wn * 64 + nt * 32 + (lane & 31);
        pvs[slot][ql][0] = v1[nt]; pis[slot][ql][0] = i1[nt];
        pvs[slot][ql][1] = v2[nt]; pis[slot][ql][1] = i2[nt];
        pvs[slot][ql][2] = v3[nt]; pis[slot][ql][2] = i3[nt];
    }
    __syncthreads();
    if (tid < 128) {
        float b1 = -FLT_MAX, b2 = -FLT_MAX, b3 = -FLT_MAX; int j1 = 0, j2 = 0, j3 = 0;
#pragma unroll
        for (int sl = 0; sl < 4; ++sl)
#pragma unroll
            for (int j = 0; j < 3; ++j) {
                float v = pvs[sl][tid][j]; int c = pis[sl][tid][j];
                if (v > b3) ins3(v, c, b1, j1, b2, j2, b3, j3);
            }
        size_t o = ((size_t)cs * NQ_TOTAL + qt * 128 + tid) * 3;
        pval[o] = b1; pval[o + 1] = b2; pval[o + 2] = b3;
        pidx[o] = j1; pidx[o + 1] = j2; pidx[o + 2] = j3;
    }
}

// ---------------------------------------------------------------- exact rescore + gather + loss
// one wave per query; 24 approx candidates -> top3 -> exact fp32 rescore
__global__ __launch_bounds__(256) void finalize_q(
        const float* __restrict__ X, const float* __restrict__ ET,
        const float* __restrict__ norms, const float* __restrict__ pval,
        const int* __restrict__ pidx, float* __restrict__ outq,
        float* __restrict__ out_idx_f, float* __restrict__ loss_q,
        int* __restrict__ counts) {
    const int lane = threadIdx.x & 63, w = threadIdx.x >> 6;
    const int q = blockIdx.x * 4 + w;
    float4 x4 = *(const float4*)&X[(size_t)q * DIM + lane * 4];

    float b1 = -FLT_MAX, b2 = -FLT_MAX, b3 = -FLT_MAX; int j1 = 0, j2 = 0, j3 = 0;
#pragma unroll
    for (int cs = 0; cs < CSPLIT; ++cs) {
        size_t o = ((size_t)cs * NQ_TOTAL + q) * 3;
#pragma unroll
        for (int j = 0; j < 3; ++j) {
            float v = pval[o + j]; int c = pidx[o + j];
            if (v > b3) ins3(v, c, b1, j1, b2, j2, b3, j3);
        }
    }
    int cands[3] = {j1, j2, j3};
    float sbest = -FLT_MAX; int kbest = 0; float4 ebest = x4;
#pragma unroll
    for (int t = 0; t < 3; ++t) {
        int k = cands[t];
        float4 e4 = *(const float4*)&ET[(size_t)k * DIM + lane * 4];
        float p = x4.x * e4.x + x4.y * e4.y + x4.z * e4.z + x4.w * e4.w;
#pragma unroll
        for (int off = 1; off < 64; off <<= 1) p += __shfl_xor(p, off);
        float s = 2.f * p - norms[k];
        bool better = (s > sbest) || (s == sbest && k < kbest);
        if (better) { sbest = s; kbest = k; ebest = e4; }
    }
    float4 d4 = {ebest.x - x4.x, ebest.y - x4.y, ebest.z - x4.z, ebest.w - x4.w};
    float4 o4 = {x4.x + d4.x, x4.y + d4.y, x4.z + d4.z, x4.w + d4.w};  // matches ref x + (q - x)
    *(float4*)&outq[(size_t)q * DIM + lane * 4] = o4;
    float l = d4.x * d4.x + d4.y * d4.y + d4.z * d4.z + d4.w * d4.w;
#pragma unroll
    for (int off = 1; off < 64; off <<= 1) l += __shfl_xor(l, off);
    if (lane == 0) {
        out_idx_f[q] = (float)kbest;
        loss_q[q] = l;
        atomicAdd(&counts[kbest], 1);
    }
}

// ---------------------------------------------------------------- scalars
__global__ __launch_bounds__(256) void final_scalars(
        const int* __restrict__ counts, const float* __restrict__ loss_q,
        float* __restrict__ out_sc) {
    int t = threadIdx.x;
    float ls = 0.f;
    for (int i = t; i < NQ_TOTAL; i += 256) ls += loss_q[i];
    float ent = 0.f;
    for (int k = t; k < K_CODES; k += 256) {
        float p = (float)counts[k] / (float)NQ_TOTAL;
        ent -= p * logf(p + 1e-10f);
    }
#pragma unroll
    for (int off = 1; off < 64; off <<= 1) { ls += __shfl_xor(ls, off); ent += __shfl_xor(ent, off); }
    __shared__ float rl[4], re[4];
    if ((t & 63) == 0) { rl[t >> 6] = ls; re[t >> 6] = ent; }
    __syncthreads();
    if (t == 0) {
        float L = rl[0] + rl[1] + rl[2] + rl[3];
        float Ee = re[0] + re[1] + re[2] + re[3];
        float mse = L / (float)((size_t)NQ_TOTAL * DIM);
        out_sc[0] = 1.1f * mse;                         // e_latent + 0.1*q_latent
        out_sc[1] = -0.1f * (Ee / logf((float)K_CODES));
    }
}

extern "C" void kernel_launch(void* const* d_in, const int* in_sizes, int n_in,
                              void* d_out, int out_size, void* d_ws, size_t ws_size,
                              hipStream_t stream) {
    const float* X = (const float*)d_in[0];   // [32768, 256] fp32
    const float* E = (const float*)d_in[1];   // [256, 8192]  fp32

    float* out       = (float*)d_out;
    float* outq      = out;                           // 8388608
    float* out_idx_f = out + (size_t)NQ_TOTAL * DIM;  // 32768 (indices as f32)
    float* out_sc    = out_idx_f + NQ_TOTAL;          // 2 scalars

    char* ws = (char*)d_ws;
    int*            counts = (int*)(ws + WS_COUNTS);
    float*          loss_q = (float*)(ws + WS_LOSSQ);
    float*          norms  = (float*)(ws + WS_NORMS);
    float*          pval   = (float*)(ws + WS_PVAL);
    int*            pidx   = (int*)(ws + WS_PIDX);
    float*          ET     = (float*)(ws + WS_ET);
    unsigned short* Ahi    = (unsigned short*)(ws + WS_AHI);
    unsigned short* Alo    = (unsigned short*)(ws + WS_ALO);
    unsigned short* Bhi    = (unsigned short*)(ws + WS_BHI);
    unsigned short* Blo    = (unsigned short*)(ws + WS_BLO);

    hipMemsetAsync(counts, 0, K_CODES * sizeof(int), stream);
    norms_kernel<<<K_CODES / 256, 256, 0, stream>>>(E, norms);
    pack_X<<<(NQ_TOTAL * 32) / 256, 256, 0, stream>>>(X, Bhi, Blo);
    pack_E<<<(K_CODES * 32) / 256, 256, 0, stream>>>(E, Ahi, Alo, ET);
    argmax_mfma<<<dim3(CSPLIT, NQ_TOTAL / TQ), 256, 0, stream>>>(Ahi, Alo, Bhi, Blo, norms, pval, pidx);
    finalize_q<<<NQ_TOTAL / 4, 256, 0, stream>>>(X, ET, norms, pval, pidx, outq, out_idx_f, loss_q, counts);
    final_scalars<<<1, 256, 0, stream>>>(counts, loss_q, out_sc);
}